// Round 18
// baseline (208.917 us; speedup 1.0000x reference)
//
#include <hip/hip_runtime.h>
#include <hip/hip_bf16.h>

#define NNODES 90112
#define BGRAPH 4096
#define NPG 22
#define DBB 256
#define DNODE 128
#define DPROJ 256
#define DGIN 64
#define DGOUT 128
#define NBLK (NNODES / 64)

// ws bf16 layout (identical to rounds 10-17):
//   [0, 32768)        WTp  [256 cols][128 k]
//   [32768, 622592)   Wpk  gate weights DMA-packed: elem ((kc*48+ct)*64+lane)*8+e
//   [622592, 688128)  Whhpk
// f32 tail: bz[256], br[256], bh[256]
// then (if ws_size permits) ws2: per-block z partial sums [NBLK][4][256] f32
#define WTG_OFF   32768
#define WTHH_OFF  622592
#define WS_BF16_ELEMS 688128
#define WS2_BYTE_OFF ((size_t)WS_BF16_ELEMS * 2 + 768 * 4)
#define WS2_BYTES    ((size_t)NBLK * 4 * 256 * 4)
#define WS_NEED      (WS2_BYTE_OFF + WS2_BYTES)

typedef __attribute__((ext_vector_type(8))) short bf16x8;
typedef __attribute__((ext_vector_type(4))) short bf16x4;
typedef __attribute__((ext_vector_type(4))) float f32x4;
typedef __attribute__((ext_vector_type(2))) float f32x2;

__device__ __forceinline__ short f2bf(float f) {
  __hip_bfloat16 h = __float2bfloat16(f);
  return *reinterpret_cast<short*>(&h);
}
__device__ __forceinline__ float bf2f(short s) {
  union { unsigned int u; float f; } c;
  c.u = ((unsigned int)(unsigned short)s) << 16;
  return c.f;
}
__device__ __forceinline__ float fsig(float xv) {
  return __fdividef(1.0f, 1.0f + __expf(-xv));
}
__device__ __forceinline__ float ftanh(float xv) {
  return 1.0f - __fdividef(2.0f, __expf(2.0f * xv) + 1.0f);
}
__device__ __forceinline__ bf16x8 pack8(f32x4 a, f32x4 b) {
  bf16x8 o;
  o[0]=f2bf(a[0]); o[1]=f2bf(a[1]); o[2]=f2bf(a[2]); o[3]=f2bf(a[3]);
  o[4]=f2bf(b[0]); o[5]=f2bf(b[1]); o[6]=f2bf(b[2]); o[7]=f2bf(b[3]);
  return o;
}

#define DMA16(gsrc, ldst)                                                        \
  __builtin_amdgcn_global_load_lds(                                              \
      (const __attribute__((address_space(1))) void*)(gsrc),                     \
      (__attribute__((address_space(3))) void*)(ldst), 16, 0, 0)

// asm-pinned 16B global load (position in vmcnt FIFO is guaranteed)
#define GLF(dst, p) asm volatile("global_load_dwordx4 %0, %1, off"               \
                                 : "=&v"(dst) : "v"(p) : "memory")

template<int N>
__device__ __forceinline__ void vmwaitN() {
  static_assert(N >= 0 && N <= 8, "vmcnt range");
  if constexpr (N == 0) asm volatile("s_waitcnt vmcnt(0)" ::: "memory");
  else if constexpr (N == 1) asm volatile("s_waitcnt vmcnt(1)" ::: "memory");
  else if constexpr (N == 2) asm volatile("s_waitcnt vmcnt(2)" ::: "memory");
  else if constexpr (N == 3) asm volatile("s_waitcnt vmcnt(3)" ::: "memory");
  else if constexpr (N == 4) asm volatile("s_waitcnt vmcnt(4)" ::: "memory");
  else if constexpr (N == 5) asm volatile("s_waitcnt vmcnt(5)" ::: "memory");
  else if constexpr (N == 6) asm volatile("s_waitcnt vmcnt(6)" ::: "memory");
  else if constexpr (N == 7) asm volatile("s_waitcnt vmcnt(7)" ::: "memory");
  else asm volatile("s_waitcnt vmcnt(8)" ::: "memory");
  __builtin_amdgcn_sched_barrier(0);
}
#define LBAR() do { asm volatile("s_waitcnt lgkmcnt(0)" ::: "memory");           \
                    __builtin_amdgcn_s_barrier(); } while (0)

__global__ void pack_weights(const float* __restrict__ w_proj,
                             const float* __restrict__ W_xz, const float* __restrict__ W_hz,
                             const float* __restrict__ W_xr, const float* __restrict__ W_hr,
                             const float* __restrict__ W_xh, const float* __restrict__ W_hh,
                             const float* __restrict__ b_xz, const float* __restrict__ b_hz,
                             const float* __restrict__ b_xr, const float* __restrict__ b_hr,
                             const float* __restrict__ b_xh, const float* __restrict__ b_hh,
                             __hip_bfloat16* __restrict__ wsb, float* __restrict__ wsf) {
  int i = blockIdx.x * 256 + threadIdx.x;
  if (i < 32768) {
    int c = i >> 7, k = i & 127;
    wsb[i] = __float2bfloat16(w_proj[k * DPROJ + c]);
  } else if (i < WTHH_OFF) {
    int j = i - WTG_OFF;
    int kc  = j / 24576;
    int rem = j - kc * 24576;
    int ct  = rem >> 9;
    int q   = rem & 511;
    int l   = q >> 3, e = q & 7;
    int l15 = l & 15, kg = l >> 4;
    int k   = kc * 32 + kg * 8 + e;
    int g   = ct >> 4;
    int c   = (ct & 15) * 16 + l15;
    float v;
    if (g == 0)      v = (k < 512) ? W_xz[k * 256 + c] : W_hz[(k - 512) * 256 + c];
    else if (g == 1) v = (k < 512) ? W_xr[k * 256 + c] : W_hr[(k - 512) * 256 + c];
    else             v = (k < 512) ? W_xh[k * 256 + c] : 0.0f;
    wsb[i] = __float2bfloat16(v);
  } else if (i < WS_BF16_ELEMS) {
    int j = i - WTHH_OFF;
    int kc  = j >> 13;
    int rem = j & 8191;
    int ct  = rem >> 9;
    int q   = rem & 511;
    int l   = q >> 3, e = q & 7;
    int l15 = l & 15, kg = l >> 4;
    int k   = kc * 32 + kg * 8 + e;
    int c   = ct * 16 + l15;
    wsb[i] = __float2bfloat16(W_hh[k * 256 + c]);
  }
  if (i < 256) {
    wsf[i]       = b_xz[i] + b_hz[i];
    wsf[256 + i] = b_xr[i] + b_hr[i];
    wsf[512 + i] = b_xh[i] + b_hh[i];
  }
}

// fallback head (reads z directly) — used when ws is too small for ws2
__global__ void fused_head(const float* __restrict__ z, const float* __restrict__ u,
                           const float* __restrict__ w_glob, const float* __restrict__ b_glob,
                           float* __restrict__ out) {
  int b = blockIdx.x;
  int t = threadIdx.x;  // 128
  __shared__ float us[DGIN];
  if (t < DGIN) us[t] = u[b * DGIN + t];
  __syncthreads();
  const float* zb = z + (size_t)b * NPG * DBB;
  #pragma unroll
  for (int half = 0; half < 2; ++half) {
    int c = t + half * 128;
    float s = 0.f;
    #pragma unroll
    for (int r = 0; r < NPG; ++r) s += zb[r * DBB + c];
    out[(size_t)b * 384 + c] = s * (1.0f / NPG);
  }
  float acc = b_glob[t];
  #pragma unroll
  for (int k = 0; k < DGIN; ++k) acc += us[k] * w_glob[k * DGOUT + t];
  out[(size_t)b * 384 + 256 + t] = fmaxf(acc, 0.f);
}

// head2: reduce per-block z partial sums (<=2 blocks per graph) + glob proj
__global__ void head2(const float* __restrict__ u,
                      const float* __restrict__ w_glob, const float* __restrict__ b_glob,
                      const float* __restrict__ ws2, float* __restrict__ out) {
  int b = blockIdx.x;   // graph
  int t = threadIdx.x;  // 128
  __shared__ float us[DGIN];
  if (t < DGIN) us[t] = u[b * DGIN + t];
  __syncthreads();
  const int rlo = b * NPG, rhi = b * NPG + NPG - 1;
  const int b0 = rlo >> 6, b1 = rhi >> 6;
  const int gl0 = b - (b0 * 64) / NPG;
  #pragma unroll
  for (int half = 0; half < 2; ++half) {
    int c = t + half * 128;
    float s = ws2[((size_t)b0 * 4 + gl0) * 256 + c];
    if (b1 != b0) {
      const int gl1 = b - (b1 * 64) / NPG;
      s += ws2[((size_t)b1 * 4 + gl1) * 256 + c];
    }
    out[(size_t)b * 384 + c] = s * (1.0f / NPG);
  }
  float acc = b_glob[t];
  #pragma unroll
  for (int k = 0; k < DGIN; ++k) acc += us[k] * w_glob[k * DGOUT + t];
  out[(size_t)b * 384 + 256 + t] = fmaxf(acc, 0.f);
}

#define MFMA16(a, b, c) __builtin_amdgcn_mfma_f32_16x16x32_bf16(a, b, c, 0, 0, 0)

// One gate-sweep chunk. No staging inside; exact-counted single vmwait.
template<int KC>
__device__ __forceinline__ void gstep(
    const __hip_bfloat16* __restrict__ wpk, __hip_bfloat16* Wb,
    const __hip_bfloat16* Av, const __hip_bfloat16* XP,
    int l15, int lg, int wid, int lane,
    f32x4 (&accz)[4], f32x4 (&accr)[4], f32x4 (&acch)[4]) {
  constexpr bool has_h = (KC < 16);
  constexpr int NW = (KC <= 8) ? 3
                   : (KC == 9 || KC == 10 || KC == 12 || KC == 13) ? 5
                   : (KC == 11 || KC == 14) ? 3
                   : (KC <= 22) ? 2 : 0;
  const __hip_bfloat16* ab = (KC >= 8 && KC < 16) ? XP : Av;
  const int gk = (KC & 7) * 4 + lg;
  bf16x8 act[4];
  #pragma unroll
  for (int rt = 0; rt < 4; ++rt) {
    const int row = rt * 16 + l15;
    act[rt] = *(const bf16x8*)(ab + row * 256 + ((gk ^ (row & 7)) * 8));
  }
  vmwaitN<NW>();
  bf16x8 wz = *(const bf16x8*)&Wb[((KC & 1) * 3 + 0) * 8192 + wid * 512 + lane * 8];
  bf16x8 wr = *(const bf16x8*)&Wb[((KC & 1) * 3 + 1) * 8192 + wid * 512 + lane * 8];
  bf16x8 wh;
  if constexpr (has_h)
    wh = *(const bf16x8*)&Wb[((KC & 1) * 3 + 2) * 8192 + wid * 512 + lane * 8];
  __builtin_amdgcn_s_setprio(1);
  #pragma unroll
  for (int rt = 0; rt < 4; ++rt) {
    accz[rt] = MFMA16(wz, act[rt], accz[rt]);
    accr[rt] = MFMA16(wr, act[rt], accr[rt]);
    if constexpr (has_h) acch[rt] = MFMA16(wh, act[rt], acch[rt]);
  }
  __builtin_amdgcn_s_setprio(0);
  if constexpr (KC + 2 <= 23) {
    constexpr int ns = ((KC + 2) < 16) ? 3 : 2;
    #pragma unroll
    for (int g = 0; g < 3; ++g)
      if (g < ns)
        DMA16(wpk + (((size_t)(KC + 2) * 48 + g * 16 + wid) * 64 + lane) * 8,
              Wb + (((KC + 2) & 1) * 3 + g) * 8192 + wid * 512);
  }
}

// One Whh step (ring-4 slots, depth-3 DMA).
template<int S>
__device__ __forceinline__ void hstep(
    const __hip_bfloat16* __restrict__ hpk, __hip_bfloat16* Wb, __hip_bfloat16* XP,
    int l15, int lg, int wid, int lane, f32x4 (&acch)[4]) {
  constexpr int NW = (S <= 5) ? 2 : (S == 6) ? 1 : 0;
  bf16x8 act[4];
  #pragma unroll
  for (int rt = 0; rt < 4; ++rt) {
    const int row = rt * 16 + l15;
    const int gk = S * 4 + lg;
    act[rt] = *(const bf16x8*)&XP[row * 256 + ((gk ^ (row & 7)) * 8)];
  }
  vmwaitN<NW>();
  bf16x8 w = *(const bf16x8*)&Wb[(S % 4) * 8192 + wid * 512 + lane * 8];
  __builtin_amdgcn_s_setprio(1);
  #pragma unroll
  for (int rt = 0; rt < 4; ++rt) acch[rt] = MFMA16(w, act[rt], acch[rt]);
  __builtin_amdgcn_s_setprio(0);
  if constexpr (S + 3 <= 7)
    DMA16(hpk + (((size_t)(S + 3) * 16 + wid) * 64 + lane) * 8,
          Wb + ((S + 3) % 4) * 8192 + wid * 512);
}

// GRU body: 64 rows/block, 1024 thr (16 waves x 16 gate-cols, 48 f32 acc/lane).
// Full-tile act staging (z, ph in Av; xp in XP): only 2 in-sweep barriers.
// If ws2 != nullptr, also writes per-block z partial sums (non-atomic, 4KB).
__global__ __launch_bounds__(1024)
void grnn_main(const float* __restrict__ z, const float* __restrict__ x,
               const float* __restrict__ prev_h, const float* __restrict__ b_proj,
               const __hip_bfloat16* __restrict__ wsb, const float* __restrict__ wsf,
               float* __restrict__ ws2, float* __restrict__ h_out) {
  __shared__ __align__(16) __hip_bfloat16 Wb[6 * 8192];   // 96 KB weight slots
  __shared__ __align__(16) __hip_bfloat16 Av[64 * 256];   // 32 KB: z, then ph
  __shared__ __align__(16) __hip_bfloat16 XP[64 * 256];   // 32 KB: x (first 16K), xp, T

  const int r0   = blockIdx.x * 64;
  const int tid  = threadIdx.x;
  const int wid  = tid >> 6;
  const int lane = tid & 63;
  const int l15  = lane & 15;
  const int lg   = lane >> 4;
  const int c0   = wid * 16;
  const int cgrp = (c0 >> 3) + (lg >> 1);
  const int lgl  = (lg & 1) * 4;
  const int prow = tid >> 4;          // staging row (64 rows x 16 thread-cols)
  const int pg   = tid & 15;

  const __hip_bfloat16* wpk = wsb + WTG_OFF;
  const __hip_bfloat16* hpk = wsb + WTHH_OFF;

  // ---- P0: stage x -> XP[0:16K] as [64][128] XOR ----
  {
    const float* p = x + (size_t)(r0 + prow) * DNODE + pg * 8;
    f32x4 f0 = *(const f32x4*)p;
    f32x4 f1 = *(const f32x4*)(p + 4);
    *(bf16x8*)&XP[prow * 128 + ((pg ^ (prow & 7)) * 8)] = pack8(f0, f1);
  }
  __syncthreads();

  // ---- P1: z loads; x_proj GEMM; DMA prologue; xp+z packs ----
  f32x4 z0, z1, z2, z3;
  {
    const float* zb = z + (size_t)(r0 + prow) * DBB + pg * 16;
    z0 = *(const f32x4*)zb;       z1 = *(const f32x4*)(zb + 4);
    z2 = *(const f32x4*)(zb + 8); z3 = *(const f32x4*)(zb + 12);
  }
  f32x4 accp[4] = {};
  {
    const __hip_bfloat16* wp0 = wsb + (size_t)(c0 + l15) * DNODE + lg * 8;
    #pragma unroll
    for (int kb = 0; kb < 4; ++kb) {
      bf16x8 wp = *(const bf16x8*)(wp0 + kb * 32);
      const int gk = kb * 4 + lg;
      bf16x8 act[4];
      #pragma unroll
      for (int rt = 0; rt < 4; ++rt) {
        const int row = rt * 16 + l15;
        act[rt] = *(const bf16x8*)&XP[row * 128 + ((gk ^ (row & 7)) * 8)];
      }
      __builtin_amdgcn_s_setprio(1);
      #pragma unroll
      for (int rt = 0; rt < 4; ++rt)
        accp[rt] = MFMA16(wp, act[rt], accp[rt]);
      __builtin_amdgcn_s_setprio(0);
    }
  }
  // weight DMA prologue: chunks 0 (slots 0-2), 1 (slots 3-5)
  #pragma unroll
  for (int c = 0; c < 2; ++c)
    #pragma unroll
    for (int g = 0; g < 3; ++g)
      DMA16(wpk + (((size_t)c * 48 + g * 16 + wid) * 64 + lane) * 8,
            Wb + ((c & 1) * 3 + g) * 8192 + wid * 512);
  LBAR();   // all x reads done -> XP overwrite safe
  // xp -> XP (full [64][256] XOR layout)
  {
    float4 bp4 = *(const float4*)&b_proj[c0 + lg * 4];
    #pragma unroll
    for (int rt = 0; rt < 4; ++rt) {
      int r = rt * 16 + l15;
      bf16x4 o;
      o[0] = f2bf(fmaxf(accp[rt][0] + bp4.x, 0.f));
      o[1] = f2bf(fmaxf(accp[rt][1] + bp4.y, 0.f));
      o[2] = f2bf(fmaxf(accp[rt][2] + bp4.z, 0.f));
      o[3] = f2bf(fmaxf(accp[rt][3] + bp4.w, 0.f));
      *(bf16x4*)&XP[r * 256 + ((cgrp ^ (r & 7)) * 8) + lgl] = o;
    }
  }
  // z -> Av (compiler emits exact vmcnt wait for z loads; DMAs stay in flight)
  *(bf16x8*)&Av[prow * 256 + (((2 * pg) ^ (prow & 7)) * 8)]     = pack8(z0, z1);
  *(bf16x8*)&Av[prow * 256 + (((2 * pg + 1) ^ (prow & 7)) * 8)] = pack8(z2, z3);
  LBAR();   // xp + z visible; FIFO = [ch0(3), ch1(3)]

  // ---- P1.5: per-graph z partial sums -> ws2 (non-atomic; hides under the
  // prologue DMA latency). The single store makes later counted vmwaits
  // strictly more conservative (extra FIFO entry), never less.
  if (ws2 != nullptr && tid < 512) {
    const int gl = tid >> 7;             // 0..3
    const int cp = tid & 127;            // column pair
    const int g  = r0 / NPG + gl;
    float s0 = 0.f, s1 = 0.f;
    if (g < BGRAPH) {
      int lo = g * NPG - r0;       if (lo < 0) lo = 0;
      int hi = g * NPG + NPG - r0; if (hi > 64) hi = 64;
      const int c  = 2 * cp;
      const int cg = c >> 3, ce = c & 7;   // ce even -> 4B aligned
      for (int row = lo; row < hi; ++row) {
        unsigned int v = *(const unsigned int*)&Av[row * 256 + (((cg ^ (row & 7)) << 3) + ce)];
        s0 += bf2f((short)(v & 0xffff));
        s1 += bf2f((short)(v >> 16));
      }
    }
    f32x2 o = { s0, s1 };
    *(f32x2*)&ws2[((size_t)blockIdx.x * 4 + gl) * 256 + 2 * cp] = o;
  }

  // ---- P2: 24-chunk gate sweep (2 barriers total) ----
  f32x4 accz[4] = {}, accr[4] = {}, acch[4] = {};
  const float* phb = prev_h + (size_t)(r0 + prow) * DBB + pg * 8;
  f32x4 pa0, pa1, pb0, pb1;
  #define GS(K) gstep<K>(wpk, Wb, Av, XP, l15, lg, wid, lane, accz, accr, acch)
  GS(0); GS(1); GS(2); GS(3); GS(4); GS(5); GS(6); GS(7);
  LBAR();                    // z phase done -> Av overwrite (ph) safe
  GS(8);
  GLF(pa0, phb); GLF(pa1, phb + 4);              // ph k[0,128) half
  GS(9); GS(10);
  vmwaitN<6>();                                  // drain pa (ch11,ch12 = 6 younger)
  *(bf16x8*)&Av[prow * 256 + ((pg ^ (prow & 7)) * 8)] = pack8(pa0, pa1);
  GS(11);
  GLF(pb0, phb + 128); GLF(pb1, phb + 132);      // ph k[128,256) half
  GS(12); GS(13);
  vmwaitN<6>();                                  // drain pb (ch14,ch15 = 6 younger)
  *(bf16x8*)&Av[prow * 256 + (((16 + pg) ^ (prow & 7)) * 8)] = pack8(pb0, pb1);
  GS(14); GS(15);
  LBAR();                    // xp phase done; ph packs visible
  GS(16); GS(17); GS(18); GS(19); GS(20); GS(21); GS(22); GS(23);
  #undef GS

  // ---- P3: Whh DMA prologue; T = ph*sigmoid(A_r+br) -> XP; LBAR ----
  #pragma unroll
  for (int s = 0; s < 3; ++s)
    DMA16(hpk + (((size_t)s * 16 + wid) * 64 + lane) * 8, Wb + (s % 4) * 8192 + wid * 512);
  {
    float4 br4 = *(const float4*)&wsf[256 + c0 + lg * 4];
    #pragma unroll
    for (int rt = 0; rt < 4; ++rt) {
      int r = rt * 16 + l15;
      int off = r * 256 + ((cgrp ^ (r & 7)) * 8) + lgl;
      bf16x4 p4 = *(const bf16x4*)&Av[off];
      bf16x4 o;
      o[0] = f2bf(bf2f(p4[0]) * fsig(accr[rt][0] + br4.x));
      o[1] = f2bf(bf2f(p4[1]) * fsig(accr[rt][1] + br4.y));
      o[2] = f2bf(bf2f(p4[2]) * fsig(accr[rt][2] + br4.z));
      o[3] = f2bf(bf2f(p4[3]) * fsig(accr[rt][3] + br4.w));
      *(bf16x4*)&XP[off] = o;
    }
  }
  LBAR();

  // ---- P4: acch += T @ W_hh ----
  #define HS(S) hstep<S>(hpk, Wb, XP, l15, lg, wid, lane, acch)
  HS(0); HS(1); HS(2); HS(3); HS(4); HS(5); HS(6); HS(7);
  #undef HS

  // ---- epilogue: h = Z*ph + (1-Z)*tanh(A_h); ph from Av ----
  {
    float4 bz4 = *(const float4*)&wsf[c0 + lg * 4];
    float4 bh4 = *(const float4*)&wsf[512 + c0 + lg * 4];
    #pragma unroll
    for (int rt = 0; rt < 4; ++rt) {
      int r = rt * 16 + l15;
      bf16x4 p4 = *(const bf16x4*)&Av[r * 256 + ((cgrp ^ (r & 7)) * 8) + lgl];
      f32x4 hv;
      float zg = fsig(accz[rt][0] + bz4.x);
      hv[0] = zg * bf2f(p4[0]) + (1.f - zg) * ftanh(acch[rt][0] + bh4.x);
      zg = fsig(accz[rt][1] + bz4.y);
      hv[1] = zg * bf2f(p4[1]) + (1.f - zg) * ftanh(acch[rt][1] + bh4.y);
      zg = fsig(accz[rt][2] + bz4.z);
      hv[2] = zg * bf2f(p4[2]) + (1.f - zg) * ftanh(acch[rt][2] + bh4.z);
      zg = fsig(accz[rt][3] + bz4.w);
      hv[3] = zg * bf2f(p4[3]) + (1.f - zg) * ftanh(acch[rt][3] + bh4.w);
      *(f32x4*)&h_out[(size_t)(r0 + r) * DBB + c0 + lg * 4] = hv;
    }
  }
}

extern "C" void kernel_launch(void* const* d_in, const int* in_sizes, int n_in,
                              void* d_out, int out_size, void* d_ws, size_t ws_size,
                              hipStream_t stream) {
  const float* z      = (const float*)d_in[0];
  const float* u      = (const float*)d_in[1];
  const float* x      = (const float*)d_in[2];
  const float* prev_h = (const float*)d_in[6];
  const float* w_proj = (const float*)d_in[7];
  const float* b_proj = (const float*)d_in[8];
  const float* w_glob = (const float*)d_in[9];
  const float* b_glob = (const float*)d_in[10];
  const float* W_xz   = (const float*)d_in[11];
  const float* b_xz   = (const float*)d_in[12];
  const float* W_hz   = (const float*)d_in[13];
  const float* b_hz   = (const float*)d_in[14];
  const float* W_xr   = (const float*)d_in[15];
  const float* b_xr   = (const float*)d_in[16];
  const float* W_hr   = (const float*)d_in[17];
  const float* b_hr   = (const float*)d_in[18];
  const float* W_xh   = (const float*)d_in[19];
  const float* b_xh   = (const float*)d_in[20];
  const float* W_hh   = (const float*)d_in[21];
  const float* b_hh   = (const float*)d_in[22];

  __hip_bfloat16* wsb = (__hip_bfloat16*)d_ws;
  float* wsf = (float*)((char*)d_ws + (size_t)WS_BF16_ELEMS * 2);

  float* fused = (float*)d_out;
  float* h_out = fused + (size_t)BGRAPH * 384;

  const bool big_ws = (ws_size >= WS_NEED);
  float* ws2 = big_ws ? (float*)((char*)d_ws + WS2_BYTE_OFF) : nullptr;

  pack_weights<<<dim3(WS_BF16_ELEMS / 256), dim3(256), 0, stream>>>(
      w_proj, W_xz, W_hz, W_xr, W_hr, W_xh, W_hh,
      b_xz, b_hz, b_xr, b_hr, b_xh, b_hh, wsb, wsf);

  if (!big_ws) {
    // fallback: serial head (reads z directly)
    fused_head<<<dim3(BGRAPH), dim3(128), 0, stream>>>(z, u, w_glob, b_glob, fused);
  }

  grnn_main<<<dim3(NBLK), dim3(1024), 0, stream>>>(
      z, x, prev_h, b_proj, wsb, wsf, ws2, h_out);

  if (big_ws) {
    head2<<<dim3(BGRAPH), dim3(128), 0, stream>>>(u, w_glob, b_glob, ws2, fused);
  }
}

// Round 19
// 195.425 us; speedup vs baseline: 1.0690x; 1.0690x over previous
//
#include <hip/hip_runtime.h>
#include <hip/hip_bf16.h>

#define NNODES 90112
#define BGRAPH 4096
#define NPG 22
#define DBB 256
#define DNODE 128
#define DPROJ 256
#define DGIN 64
#define DGOUT 128

// ws bf16 layout (identical to rounds 10-17):
//   [0, 32768)        WTp  [256 cols][128 k]
//   [32768, 622592)   Wpk  gate weights DMA-packed: elem ((kc*48+ct)*64+lane)*8+e
//   [622592, 688128)  Whhpk
// f32 tail: bz[256], br[256], bh[256]
#define WTG_OFF   32768
#define WTHH_OFF  622592
#define WS_BF16_ELEMS 688128

typedef __attribute__((ext_vector_type(8))) short bf16x8;
typedef __attribute__((ext_vector_type(4))) short bf16x4;
typedef __attribute__((ext_vector_type(4))) float f32x4;

__device__ __forceinline__ short f2bf(float f) {
  __hip_bfloat16 h = __float2bfloat16(f);
  return *reinterpret_cast<short*>(&h);
}
__device__ __forceinline__ float bf2f(short s) {
  union { unsigned int u; float f; } c;
  c.u = ((unsigned int)(unsigned short)s) << 16;
  return c.f;
}
__device__ __forceinline__ float fsig(float xv) {
  return __fdividef(1.0f, 1.0f + __expf(-xv));
}
__device__ __forceinline__ float ftanh(float xv) {
  return 1.0f - __fdividef(2.0f, __expf(2.0f * xv) + 1.0f);
}
__device__ __forceinline__ bf16x8 pack8(f32x4 a, f32x4 b) {
  bf16x8 o;
  o[0]=f2bf(a[0]); o[1]=f2bf(a[1]); o[2]=f2bf(a[2]); o[3]=f2bf(a[3]);
  o[4]=f2bf(b[0]); o[5]=f2bf(b[1]); o[6]=f2bf(b[2]); o[7]=f2bf(b[3]);
  return o;
}

#define DMA16(gsrc, ldst)                                                        \
  __builtin_amdgcn_global_load_lds(                                              \
      (const __attribute__((address_space(1))) void*)(gsrc),                     \
      (__attribute__((address_space(3))) void*)(ldst), 16, 0, 0)

// asm-pinned 16B global load (position in vmcnt FIFO is guaranteed)
#define GLF(dst, p) asm volatile("global_load_dwordx4 %0, %1, off"               \
                                 : "=&v"(dst) : "v"(p) : "memory")

template<int N>
__device__ __forceinline__ void vmwaitN() {
  static_assert(N >= 0 && N <= 8, "vmcnt range");
  if constexpr (N == 0) asm volatile("s_waitcnt vmcnt(0)" ::: "memory");
  else if constexpr (N == 1) asm volatile("s_waitcnt vmcnt(1)" ::: "memory");
  else if constexpr (N == 2) asm volatile("s_waitcnt vmcnt(2)" ::: "memory");
  else if constexpr (N == 3) asm volatile("s_waitcnt vmcnt(3)" ::: "memory");
  else if constexpr (N == 4) asm volatile("s_waitcnt vmcnt(4)" ::: "memory");
  else if constexpr (N == 5) asm volatile("s_waitcnt vmcnt(5)" ::: "memory");
  else if constexpr (N == 6) asm volatile("s_waitcnt vmcnt(6)" ::: "memory");
  else if constexpr (N == 7) asm volatile("s_waitcnt vmcnt(7)" ::: "memory");
  else asm volatile("s_waitcnt vmcnt(8)" ::: "memory");
  __builtin_amdgcn_sched_barrier(0);
}
#define LBAR() do { asm volatile("s_waitcnt lgkmcnt(0)" ::: "memory");           \
                    __builtin_amdgcn_s_barrier(); } while (0)

__global__ void pack_weights(const float* __restrict__ w_proj,
                             const float* __restrict__ W_xz, const float* __restrict__ W_hz,
                             const float* __restrict__ W_xr, const float* __restrict__ W_hr,
                             const float* __restrict__ W_xh, const float* __restrict__ W_hh,
                             const float* __restrict__ b_xz, const float* __restrict__ b_hz,
                             const float* __restrict__ b_xr, const float* __restrict__ b_hr,
                             const float* __restrict__ b_xh, const float* __restrict__ b_hh,
                             __hip_bfloat16* __restrict__ wsb, float* __restrict__ wsf) {
  int i = blockIdx.x * 256 + threadIdx.x;
  if (i < 32768) {
    int c = i >> 7, k = i & 127;
    wsb[i] = __float2bfloat16(w_proj[k * DPROJ + c]);
  } else if (i < WTHH_OFF) {
    int j = i - WTG_OFF;
    int kc  = j / 24576;
    int rem = j - kc * 24576;
    int ct  = rem >> 9;
    int q   = rem & 511;
    int l   = q >> 3, e = q & 7;
    int l15 = l & 15, kg = l >> 4;
    int k   = kc * 32 + kg * 8 + e;
    int g   = ct >> 4;
    int c   = (ct & 15) * 16 + l15;
    float v;
    if (g == 0)      v = (k < 512) ? W_xz[k * 256 + c] : W_hz[(k - 512) * 256 + c];
    else if (g == 1) v = (k < 512) ? W_xr[k * 256 + c] : W_hr[(k - 512) * 256 + c];
    else             v = (k < 512) ? W_xh[k * 256 + c] : 0.0f;
    wsb[i] = __float2bfloat16(v);
  } else if (i < WS_BF16_ELEMS) {
    int j = i - WTHH_OFF;
    int kc  = j >> 13;
    int rem = j & 8191;
    int ct  = rem >> 9;
    int q   = rem & 511;
    int l   = q >> 3, e = q & 7;
    int l15 = l & 15, kg = l >> 4;
    int k   = kc * 32 + kg * 8 + e;
    int c   = ct * 16 + l15;
    wsb[i] = __float2bfloat16(W_hh[k * 256 + c]);
  }
  if (i < 256) {
    wsf[i]       = b_xz[i] + b_hz[i];
    wsf[256 + i] = b_xr[i] + b_hr[i];
    wsf[512 + i] = b_xh[i] + b_hh[i];
  }
}

__global__ void fused_head(const float* __restrict__ z, const float* __restrict__ u,
                           const float* __restrict__ w_glob, const float* __restrict__ b_glob,
                           float* __restrict__ out) {
  int b = blockIdx.x;
  int t = threadIdx.x;  // 128
  __shared__ float us[DGIN];
  if (t < DGIN) us[t] = u[b * DGIN + t];
  __syncthreads();
  const float* zb = z + (size_t)b * NPG * DBB;
  #pragma unroll
  for (int half = 0; half < 2; ++half) {
    int c = t + half * 128;
    float s = 0.f;
    #pragma unroll
    for (int r = 0; r < NPG; ++r) s += zb[r * DBB + c];
    out[(size_t)b * 384 + c] = s * (1.0f / NPG);
  }
  float acc = b_glob[t];
  #pragma unroll
  for (int k = 0; k < DGIN; ++k) acc += us[k] * w_glob[k * DGOUT + t];
  out[(size_t)b * 384 + 256 + t] = fmaxf(acc, 0.f);
}

#define MFMA16(a, b, c) __builtin_amdgcn_mfma_f32_16x16x32_bf16(a, b, c, 0, 0, 0)

// One gate-sweep chunk. No staging inside; exact-counted single vmwait.
template<int KC>
__device__ __forceinline__ void gstep(
    const __hip_bfloat16* __restrict__ wpk, __hip_bfloat16* Wb,
    const __hip_bfloat16* Av, const __hip_bfloat16* XP,
    int l15, int lg, int wid, int lane,
    f32x4 (&accz)[4], f32x4 (&accr)[4], f32x4 (&acch)[4]) {
  constexpr bool has_h = (KC < 16);
  constexpr int NW = (KC <= 8) ? 3
                   : (KC == 9 || KC == 10 || KC == 12 || KC == 13) ? 5
                   : (KC == 11 || KC == 14) ? 3
                   : (KC <= 22) ? 2 : 0;
  const __hip_bfloat16* ab = (KC >= 8 && KC < 16) ? XP : Av;
  const int gk = (KC & 7) * 4 + lg;
  bf16x8 act[4];
  #pragma unroll
  for (int rt = 0; rt < 4; ++rt) {
    const int row = rt * 16 + l15;
    act[rt] = *(const bf16x8*)(ab + row * 256 + ((gk ^ (row & 7)) * 8));
  }
  vmwaitN<NW>();
  bf16x8 wz = *(const bf16x8*)&Wb[((KC & 1) * 3 + 0) * 8192 + wid * 512 + lane * 8];
  bf16x8 wr = *(const bf16x8*)&Wb[((KC & 1) * 3 + 1) * 8192 + wid * 512 + lane * 8];
  bf16x8 wh;
  if constexpr (has_h)
    wh = *(const bf16x8*)&Wb[((KC & 1) * 3 + 2) * 8192 + wid * 512 + lane * 8];
  __builtin_amdgcn_s_setprio(1);
  #pragma unroll
  for (int rt = 0; rt < 4; ++rt) {
    accz[rt] = MFMA16(wz, act[rt], accz[rt]);
    accr[rt] = MFMA16(wr, act[rt], accr[rt]);
    if constexpr (has_h) acch[rt] = MFMA16(wh, act[rt], acch[rt]);
  }
  __builtin_amdgcn_s_setprio(0);
  if constexpr (KC + 2 <= 23) {
    constexpr int ns = ((KC + 2) < 16) ? 3 : 2;
    #pragma unroll
    for (int g = 0; g < 3; ++g)
      if (g < ns)
        DMA16(wpk + (((size_t)(KC + 2) * 48 + g * 16 + wid) * 64 + lane) * 8,
              Wb + (((KC + 2) & 1) * 3 + g) * 8192 + wid * 512);
  }
}

// One Whh step (ring-4 slots, depth-3 DMA).
template<int S>
__device__ __forceinline__ void hstep(
    const __hip_bfloat16* __restrict__ hpk, __hip_bfloat16* Wb, __hip_bfloat16* XP,
    int l15, int lg, int wid, int lane, f32x4 (&acch)[4]) {
  constexpr int NW = (S <= 5) ? 2 : (S == 6) ? 1 : 0;
  bf16x8 act[4];
  #pragma unroll
  for (int rt = 0; rt < 4; ++rt) {
    const int row = rt * 16 + l15;
    const int gk = S * 4 + lg;
    act[rt] = *(const bf16x8*)&XP[row * 256 + ((gk ^ (row & 7)) * 8)];
  }
  vmwaitN<NW>();
  bf16x8 w = *(const bf16x8*)&Wb[(S % 4) * 8192 + wid * 512 + lane * 8];
  __builtin_amdgcn_s_setprio(1);
  #pragma unroll
  for (int rt = 0; rt < 4; ++rt) acch[rt] = MFMA16(w, act[rt], acch[rt]);
  __builtin_amdgcn_s_setprio(0);
  if constexpr (S + 3 <= 7)
    DMA16(hpk + (((size_t)(S + 3) * 16 + wid) * 64 + lane) * 8,
          Wb + ((S + 3) % 4) * 8192 + wid * 512);
}

// GRU body: 64 rows/block, 1024 thr (16 waves x 16 gate-cols, 48 f32 acc/lane).
// Full-tile act staging (z, ph in Av; xp in XP): only 2 in-sweep barriers.
__global__ __launch_bounds__(1024)
void grnn_main(const float* __restrict__ z, const float* __restrict__ x,
               const float* __restrict__ prev_h, const float* __restrict__ b_proj,
               const __hip_bfloat16* __restrict__ wsb, const float* __restrict__ wsf,
               float* __restrict__ h_out) {
  __shared__ __align__(16) __hip_bfloat16 Wb[6 * 8192];   // 96 KB weight slots
  __shared__ __align__(16) __hip_bfloat16 Av[64 * 256];   // 32 KB: z, then ph
  __shared__ __align__(16) __hip_bfloat16 XP[64 * 256];   // 32 KB: x (first 16K), xp, T

  const int r0   = blockIdx.x * 64;
  const int tid  = threadIdx.x;
  const int wid  = tid >> 6;
  const int lane = tid & 63;
  const int l15  = lane & 15;
  const int lg   = lane >> 4;
  const int c0   = wid * 16;
  const int cgrp = (c0 >> 3) + (lg >> 1);
  const int lgl  = (lg & 1) * 4;
  const int prow = tid >> 4;          // staging row (64 rows x 16 thread-cols)
  const int pg   = tid & 15;

  const __hip_bfloat16* wpk = wsb + WTG_OFF;
  const __hip_bfloat16* hpk = wsb + WTHH_OFF;

  // ---- P0: stage x -> XP[0:16K] as [64][128] XOR ----
  {
    const float* p = x + (size_t)(r0 + prow) * DNODE + pg * 8;
    f32x4 f0 = *(const f32x4*)p;
    f32x4 f1 = *(const f32x4*)(p + 4);
    *(bf16x8*)&XP[prow * 128 + ((pg ^ (prow & 7)) * 8)] = pack8(f0, f1);
  }
  __syncthreads();

  // ---- P1: z loads; x_proj GEMM; DMA prologue; xp+z packs ----
  f32x4 z0, z1, z2, z3;
  {
    const float* zb = z + (size_t)(r0 + prow) * DBB + pg * 16;
    z0 = *(const f32x4*)zb;       z1 = *(const f32x4*)(zb + 4);
    z2 = *(const f32x4*)(zb + 8); z3 = *(const f32x4*)(zb + 12);
  }
  f32x4 accp[4] = {};
  {
    const __hip_bfloat16* wp0 = wsb + (size_t)(c0 + l15) * DNODE + lg * 8;
    #pragma unroll
    for (int kb = 0; kb < 4; ++kb) {
      bf16x8 wp = *(const bf16x8*)(wp0 + kb * 32);
      const int gk = kb * 4 + lg;
      bf16x8 act[4];
      #pragma unroll
      for (int rt = 0; rt < 4; ++rt) {
        const int row = rt * 16 + l15;
        act[rt] = *(const bf16x8*)&XP[row * 128 + ((gk ^ (row & 7)) * 8)];
      }
      __builtin_amdgcn_s_setprio(1);
      #pragma unroll
      for (int rt = 0; rt < 4; ++rt)
        accp[rt] = MFMA16(wp, act[rt], accp[rt]);
      __builtin_amdgcn_s_setprio(0);
    }
  }
  // weight DMA prologue: chunks 0 (slots 0-2), 1 (slots 3-5)
  #pragma unroll
  for (int c = 0; c < 2; ++c)
    #pragma unroll
    for (int g = 0; g < 3; ++g)
      DMA16(wpk + (((size_t)c * 48 + g * 16 + wid) * 64 + lane) * 8,
            Wb + ((c & 1) * 3 + g) * 8192 + wid * 512);
  LBAR();   // all x reads done -> XP overwrite safe
  // xp -> XP (full [64][256] XOR layout)
  {
    float4 bp4 = *(const float4*)&b_proj[c0 + lg * 4];
    #pragma unroll
    for (int rt = 0; rt < 4; ++rt) {
      int r = rt * 16 + l15;
      bf16x4 o;
      o[0] = f2bf(fmaxf(accp[rt][0] + bp4.x, 0.f));
      o[1] = f2bf(fmaxf(accp[rt][1] + bp4.y, 0.f));
      o[2] = f2bf(fmaxf(accp[rt][2] + bp4.z, 0.f));
      o[3] = f2bf(fmaxf(accp[rt][3] + bp4.w, 0.f));
      *(bf16x4*)&XP[r * 256 + ((cgrp ^ (r & 7)) * 8) + lgl] = o;
    }
  }
  // z -> Av (compiler emits exact vmcnt wait for z loads; DMAs stay in flight)
  *(bf16x8*)&Av[prow * 256 + (((2 * pg) ^ (prow & 7)) * 8)]     = pack8(z0, z1);
  *(bf16x8*)&Av[prow * 256 + (((2 * pg + 1) ^ (prow & 7)) * 8)] = pack8(z2, z3);
  LBAR();   // xp + z visible; FIFO = [ch0(3), ch1(3)]

  // ---- P2: 24-chunk gate sweep (2 barriers total) ----
  f32x4 accz[4] = {}, accr[4] = {}, acch[4] = {};
  const float* phb = prev_h + (size_t)(r0 + prow) * DBB + pg * 8;
  f32x4 pa0, pa1, pb0, pb1;
  #define GS(K) gstep<K>(wpk, Wb, Av, XP, l15, lg, wid, lane, accz, accr, acch)
  GS(0); GS(1); GS(2); GS(3); GS(4); GS(5); GS(6); GS(7);
  LBAR();                    // z phase done -> Av overwrite (ph) safe
  GS(8);
  GLF(pa0, phb); GLF(pa1, phb + 4);              // ph k[0,128) half
  GS(9); GS(10);
  vmwaitN<6>();                                  // drain pa (ch11,ch12 = 6 younger)
  *(bf16x8*)&Av[prow * 256 + ((pg ^ (prow & 7)) * 8)] = pack8(pa0, pa1);
  GS(11);
  GLF(pb0, phb + 128); GLF(pb1, phb + 132);      // ph k[128,256) half
  GS(12); GS(13);
  vmwaitN<6>();                                  // drain pb (ch14,ch15 = 6 younger)
  *(bf16x8*)&Av[prow * 256 + (((16 + pg) ^ (prow & 7)) * 8)] = pack8(pb0, pb1);
  GS(14); GS(15);
  LBAR();                    // xp phase done; ph packs visible
  GS(16); GS(17); GS(18); GS(19); GS(20); GS(21); GS(22); GS(23);
  #undef GS

  // ---- P3: Whh DMA prologue; T = ph*sigmoid(A_r+br) -> XP; LBAR ----
  #pragma unroll
  for (int s = 0; s < 3; ++s)
    DMA16(hpk + (((size_t)s * 16 + wid) * 64 + lane) * 8, Wb + (s % 4) * 8192 + wid * 512);
  {
    float4 br4 = *(const float4*)&wsf[256 + c0 + lg * 4];
    #pragma unroll
    for (int rt = 0; rt < 4; ++rt) {
      int r = rt * 16 + l15;
      int off = r * 256 + ((cgrp ^ (r & 7)) * 8) + lgl;
      bf16x4 p4 = *(const bf16x4*)&Av[off];
      bf16x4 o;
      o[0] = f2bf(bf2f(p4[0]) * fsig(accr[rt][0] + br4.x));
      o[1] = f2bf(bf2f(p4[1]) * fsig(accr[rt][1] + br4.y));
      o[2] = f2bf(bf2f(p4[2]) * fsig(accr[rt][2] + br4.z));
      o[3] = f2bf(bf2f(p4[3]) * fsig(accr[rt][3] + br4.w));
      *(bf16x4*)&XP[off] = o;
    }
  }
  LBAR();

  // ---- P4: acch += T @ W_hh ----
  #define HS(S) hstep<S>(hpk, Wb, XP, l15, lg, wid, lane, acch)
  HS(0); HS(1); HS(2); HS(3); HS(4); HS(5); HS(6); HS(7);
  #undef HS

  // ---- epilogue: h = Z*ph + (1-Z)*tanh(A_h); ph from Av ----
  {
    float4 bz4 = *(const float4*)&wsf[c0 + lg * 4];
    float4 bh4 = *(const float4*)&wsf[512 + c0 + lg * 4];
    #pragma unroll
    for (int rt = 0; rt < 4; ++rt) {
      int r = rt * 16 + l15;
      bf16x4 p4 = *(const bf16x4*)&Av[r * 256 + ((cgrp ^ (r & 7)) * 8) + lgl];
      f32x4 hv;
      float zg = fsig(accz[rt][0] + bz4.x);
      hv[0] = zg * bf2f(p4[0]) + (1.f - zg) * ftanh(acch[rt][0] + bh4.x);
      zg = fsig(accz[rt][1] + bz4.y);
      hv[1] = zg * bf2f(p4[1]) + (1.f - zg) * ftanh(acch[rt][1] + bh4.y);
      zg = fsig(accz[rt][2] + bz4.z);
      hv[2] = zg * bf2f(p4[2]) + (1.f - zg) * ftanh(acch[rt][2] + bh4.z);
      zg = fsig(accz[rt][3] + bz4.w);
      hv[3] = zg * bf2f(p4[3]) + (1.f - zg) * ftanh(acch[rt][3] + bh4.w);
      *(f32x4*)&h_out[(size_t)(r0 + r) * DBB + c0 + lg * 4] = hv;
    }
  }
}

extern "C" void kernel_launch(void* const* d_in, const int* in_sizes, int n_in,
                              void* d_out, int out_size, void* d_ws, size_t ws_size,
                              hipStream_t stream) {
  const float* z      = (const float*)d_in[0];
  const float* u      = (const float*)d_in[1];
  const float* x      = (const float*)d_in[2];
  const float* prev_h = (const float*)d_in[6];
  const float* w_proj = (const float*)d_in[7];
  const float* b_proj = (const float*)d_in[8];
  const float* w_glob = (const float*)d_in[9];
  const float* b_glob = (const float*)d_in[10];
  const float* W_xz   = (const float*)d_in[11];
  const float* b_xz   = (const float*)d_in[12];
  const float* W_hz   = (const float*)d_in[13];
  const float* b_hz   = (const float*)d_in[14];
  const float* W_xr   = (const float*)d_in[15];
  const float* b_xr   = (const float*)d_in[16];
  const float* W_hr   = (const float*)d_in[17];
  const float* b_hr   = (const float*)d_in[18];
  const float* W_xh   = (const float*)d_in[19];
  const float* b_xh   = (const float*)d_in[20];
  const float* W_hh   = (const float*)d_in[21];
  const float* b_hh   = (const float*)d_in[22];

  __hip_bfloat16* wsb = (__hip_bfloat16*)d_ws;
  float* wsf = (float*)((char*)d_ws + (size_t)WS_BF16_ELEMS * 2);

  float* fused = (float*)d_out;
  float* h_out = fused + (size_t)BGRAPH * 384;

  pack_weights<<<dim3(WS_BF16_ELEMS / 256), dim3(256), 0, stream>>>(
      w_proj, W_xz, W_hz, W_xr, W_hr, W_xh, W_hh,
      b_xz, b_hz, b_xr, b_hr, b_xh, b_hh, wsb, wsf);

  fused_head<<<dim3(BGRAPH), dim3(128), 0, stream>>>(z, u, w_glob, b_glob, fused);

  grnn_main<<<dim3(NNODES / 64), dim3(1024), 0, stream>>>(
      z, x, prev_h, b_proj, wsb, wsf, h_out);
}